// Round 1
// baseline (691.783 us; speedup 1.0000x reference)
//
#include <hip/hip_runtime.h>
#include <hip/hip_bf16.h>
#include <math.h>

// Problem constants (fixed by the reference's setup_inputs)
#define NB    2
#define LQ    17821
#define LIN   17821
#define CCH   256
#define HDN   8
#define DCH   32
#define LVL   4
#define NPT   4

__constant__ const int cH[LVL] = {100, 50, 25, 13};
__constant__ const int cW[LVL] = {134, 67, 34, 17};
__constant__ const int cS[LVL] = {0, 13400, 16750, 17600};

// ---------------------------------------------------------------------------
// Classic fp32 SGEMM: C[M,N] = A[M,K] @ B[K,N] + bias[N]
// BM=BN=128, BK=8, 256 threads, 8x8 microtile. Requires N%128==0, K%8==0.
// M is bounds-checked.
// ---------------------------------------------------------------------------
#define BM 128
#define BN 128
#define BK 8
#define TM 8
#define TN 8

__global__ __launch_bounds__(256, 2) void gemm_f32(
    const float* __restrict__ A, const float* __restrict__ B,
    const float* __restrict__ bias, float* __restrict__ C,
    int M, int N, int K)
{
    __shared__ float As[BK][BM];   // A tile stored transposed: As[k][m]
    __shared__ float Bs[BK][BN];

    const int tid = threadIdx.x;
    const int bm = blockIdx.y * BM;
    const int bn = blockIdx.x * BN;

    const int tr = (tid >> 4) * TM;   // 0..120, row offset in tile
    const int tc = (tid & 15) * TN;   // 0..120, col offset in tile

    // A staging: each thread loads float4; row = tid/2 (0..127), col = (tid&1)*4
    const int a_r = tid >> 1;
    const int a_c = (tid & 1) * 4;
    // B staging: row = tid/32 (0..7), col = (tid&31)*4
    const int b_r = tid >> 5;
    const int b_c = (tid & 31) * 4;

    float acc[TM][TN] = {};

    for (int k0 = 0; k0 < K; k0 += BK) {
        float4 av = make_float4(0.f, 0.f, 0.f, 0.f);
        if (bm + a_r < M)
            av = *reinterpret_cast<const float4*>(&A[(size_t)(bm + a_r) * K + k0 + a_c]);
        As[a_c + 0][a_r] = av.x;
        As[a_c + 1][a_r] = av.y;
        As[a_c + 2][a_r] = av.z;
        As[a_c + 3][a_r] = av.w;

        float4 bv4 = *reinterpret_cast<const float4*>(&B[(size_t)(k0 + b_r) * N + bn + b_c]);
        *reinterpret_cast<float4*>(&Bs[b_r][b_c]) = bv4;

        __syncthreads();

#pragma unroll
        for (int kk = 0; kk < BK; ++kk) {
            float4 a0 = *reinterpret_cast<const float4*>(&As[kk][tr]);
            float4 a1 = *reinterpret_cast<const float4*>(&As[kk][tr + 4]);
            float4 b0 = *reinterpret_cast<const float4*>(&Bs[kk][tc]);
            float4 b1 = *reinterpret_cast<const float4*>(&Bs[kk][tc + 4]);
            const float ar[TM] = {a0.x, a0.y, a0.z, a0.w, a1.x, a1.y, a1.z, a1.w};
            const float bc[TN] = {b0.x, b0.y, b0.z, b0.w, b1.x, b1.y, b1.z, b1.w};
#pragma unroll
            for (int i = 0; i < TM; ++i)
#pragma unroll
                for (int j = 0; j < TN; ++j)
                    acc[i][j] = fmaf(ar[i], bc[j], acc[i][j]);
        }
        __syncthreads();
    }

#pragma unroll
    for (int i = 0; i < TM; ++i) {
        const int row = bm + tr + i;
        if (row < M) {
#pragma unroll
            for (int j = 0; j < TN; j += 4) {
                const int col = bn + tc + j;
                float4 v;
                v.x = acc[i][j + 0] + bias[col + 0];
                v.y = acc[i][j + 1] + bias[col + 1];
                v.z = acc[i][j + 2] + bias[col + 2];
                v.w = acc[i][j + 3] + bias[col + 3];
                *reinterpret_cast<float4*>(&C[(size_t)row * N + col]) = v;
            }
        }
    }
}

// ---------------------------------------------------------------------------
// Deformable-attention sampling.
// One block (256 threads) per query row r = n*LQ + q.
// Thread t: head h = t>>5, channel d = t&31.
// offs  : [M, 256] raw offsets   (h*32 + l*8 + p*2 + {x,y})
// attr  : [M, 128] raw attention (h*16 + l*4 + p), softmax over 16 per head
// value : [M, 256] (n*LIN + pos, h*32 + d)
// refp  : [M, 8]   (l*2 + {x,y})
// out   : [M, 256]
// ---------------------------------------------------------------------------
__global__ __launch_bounds__(256) void msda_sample(
    const float* __restrict__ value,
    const float* __restrict__ offs,
    const float* __restrict__ attr,
    const float* __restrict__ refp,
    float* __restrict__ out)
{
    __shared__ float offL[256];
    __shared__ float attL[128];
    __shared__ float refL[8];

    const int r = blockIdx.x;
    const int n = r / LQ;
    const int t = threadIdx.x;

    offL[t] = offs[(size_t)r * 256 + t];
    if (t < 128) attL[t] = attr[(size_t)r * 128 + t];
    if (t < 8)   refL[t] = refp[(size_t)r * 8 + t];
    __syncthreads();

    const int h = t >> 5;
    const int d = t & 31;

    // softmax over the 16 (l,p) logits of head h (redundant across 32 lanes)
    float av[16];
    float m = -INFINITY;
#pragma unroll
    for (int i = 0; i < 16; ++i) {
        av[i] = attL[h * 16 + i];
        m = fmaxf(m, av[i]);
    }
    float s = 0.f;
#pragma unroll
    for (int i = 0; i < 16; ++i) {
        av[i] = __expf(av[i] - m);
        s += av[i];
    }
    const float inv = 1.f / s;

    float acc = 0.f;
    const float* vbase = value + (size_t)n * LIN * CCH + h * DCH + d;

#pragma unroll
    for (int l = 0; l < LVL; ++l) {
        const int   Hh = cH[l], Ww = cW[l], st = cS[l];
        const float Hf = (float)Hh, Wf = (float)Ww;
        const float rx = refL[l * 2 + 0];
        const float ry = refL[l * 2 + 1];
#pragma unroll
        for (int p = 0; p < NPT; ++p) {
            const float ox = offL[h * 32 + l * 8 + p * 2 + 0];
            const float oy = offL[h * 32 + l * 8 + p * 2 + 1];
            const float lx = rx + ox / Wf;
            const float ly = ry + oy / Hf;
            const float x = lx * Wf - 0.5f;
            const float y = ly * Hf - 0.5f;
            const float x0f = floorf(x);
            const float y0f = floorf(y);
            const float fx = x - x0f;
            const float fy = y - y0f;
            const int x0 = (int)x0f;
            const int y0 = (int)y0f;
            const float aw = av[l * 4 + p] * inv;

            const float w00 = (1.f - fx) * (1.f - fy) * aw;
            const float w10 = fx * (1.f - fy) * aw;
            const float w01 = (1.f - fx) * fy * aw;
            const float w11 = fx * fy * aw;

            const int x1 = x0 + 1, y1 = y0 + 1;
            const bool vx0 = (x0 >= 0) & (x0 < Ww);
            const bool vx1 = (x1 >= 0) & (x1 < Ww);
            const bool vy0 = (y0 >= 0) & (y0 < Hh);
            const bool vy1 = (y1 >= 0) & (y1 < Hh);

            if (vx0 & vy0) acc = fmaf(w00, vbase[(size_t)(st + y0 * Ww + x0) * CCH], acc);
            if (vx1 & vy0) acc = fmaf(w10, vbase[(size_t)(st + y0 * Ww + x1) * CCH], acc);
            if (vx0 & vy1) acc = fmaf(w01, vbase[(size_t)(st + y1 * Ww + x0) * CCH], acc);
            if (vx1 & vy1) acc = fmaf(w11, vbase[(size_t)(st + y1 * Ww + x1) * CCH], acc);
        }
    }

    out[(size_t)r * 256 + t] = acc;
}

// ---------------------------------------------------------------------------
extern "C" void kernel_launch(void* const* d_in, const int* in_sizes, int n_in,
                              void* d_out, int out_size, void* d_ws, size_t ws_size,
                              hipStream_t stream)
{
    const float* query  = (const float*)d_in[0];
    const float* refp   = (const float*)d_in[1];
    const float* inflat = (const float*)d_in[2];
    // d_in[3] shapes, d_in[4] starts: compile-time constants, unused
    const float* Wv     = (const float*)d_in[5];
    const float* bv     = (const float*)d_in[6];
    const float* Woff   = (const float*)d_in[7];
    const float* boff   = (const float*)d_in[8];
    const float* Watt   = (const float*)d_in[9];
    const float* batt   = (const float*)d_in[10];
    const float* Wout   = (const float*)d_in[11];
    const float* bout   = (const float*)d_in[12];
    float* out = (float*)d_out;

    const int M = NB * LQ;                 // 35642
    float* ws    = (float*)d_ws;
    float* value = ws;                              // M*256
    float* offsW = value + (size_t)M * 256;         // M*256
    float* attrW = offsW + (size_t)M * 256;         // M*128
    float* oattn = attrW + (size_t)M * 128;         // M*256

    const dim3 blk(256);
    const int mblk = (M + BM - 1) / BM;    // 279

    gemm_f32<<<dim3(2, mblk), blk, 0, stream>>>(inflat, Wv,   bv,   value, M, 256, 256);
    gemm_f32<<<dim3(2, mblk), blk, 0, stream>>>(query,  Woff, boff, offsW, M, 256, 256);
    gemm_f32<<<dim3(1, mblk), blk, 0, stream>>>(query,  Watt, batt, attrW, M, 128, 256);

    msda_sample<<<dim3(M), blk, 0, stream>>>(value, offsW, attrW, refp, oattn);

    gemm_f32<<<dim3(2, mblk), blk, 0, stream>>>(oattn, Wout, bout, out, M, 256, 256);
}

// Round 2
// 607.498 us; speedup vs baseline: 1.1387x; 1.1387x over previous
//
#include <hip/hip_runtime.h>
#include <hip/hip_bf16.h>
#include <math.h>

// Problem constants (fixed by the reference's setup_inputs)
#define NB    2
#define LQ    17821
#define LIN   17821
#define CCH   256
#define HDN   8
#define DCH   32
#define LVL   4
#define NPT   4

__constant__ const int   cH[LVL]  = {100, 50, 25, 13};
__constant__ const int   cW[LVL]  = {134, 67, 34, 17};
__constant__ const int   cS[LVL]  = {0, 13400, 16750, 17600};
__constant__ const float cHf[LVL] = {100.f, 50.f, 25.f, 13.f};
__constant__ const float cWf[LVL] = {134.f, 67.f, 34.f, 17.f};
__constant__ const float cRH[LVL] = {1.f/100.f, 1.f/50.f, 1.f/25.f, 1.f/13.f};
__constant__ const float cRW[LVL] = {1.f/134.f, 1.f/67.f, 1.f/34.f, 1.f/17.f};

// ---------------------------------------------------------------------------
// Classic fp32 SGEMM: C[M,N] = A[M,K] @ B[K,N] + bias[N]
// BM=BN=128, BK=8, 256 threads, 8x8 microtile. Requires N%128==0, K%8==0.
// ---------------------------------------------------------------------------
#define BM 128
#define BN 128
#define BK 8
#define TM 8
#define TN 8

__global__ __launch_bounds__(256, 2) void gemm_f32(
    const float* __restrict__ A, const float* __restrict__ B,
    const float* __restrict__ bias, float* __restrict__ C,
    int M, int N, int K)
{
    __shared__ float As[BK][BM];   // A tile stored transposed: As[k][m]
    __shared__ float Bs[BK][BN];

    const int tid = threadIdx.x;
    const int bm = blockIdx.y * BM;
    const int bn = blockIdx.x * BN;

    const int tr = (tid >> 4) * TM;
    const int tc = (tid & 15) * TN;

    const int a_r = tid >> 1;
    const int a_c = (tid & 1) * 4;
    const int b_r = tid >> 5;
    const int b_c = (tid & 31) * 4;

    float acc[TM][TN] = {};

    for (int k0 = 0; k0 < K; k0 += BK) {
        float4 av = make_float4(0.f, 0.f, 0.f, 0.f);
        if (bm + a_r < M)
            av = *reinterpret_cast<const float4*>(&A[(size_t)(bm + a_r) * K + k0 + a_c]);
        As[a_c + 0][a_r] = av.x;
        As[a_c + 1][a_r] = av.y;
        As[a_c + 2][a_r] = av.z;
        As[a_c + 3][a_r] = av.w;

        float4 bv4 = *reinterpret_cast<const float4*>(&B[(size_t)(k0 + b_r) * N + bn + b_c]);
        *reinterpret_cast<float4*>(&Bs[b_r][b_c]) = bv4;

        __syncthreads();

#pragma unroll
        for (int kk = 0; kk < BK; ++kk) {
            float4 a0 = *reinterpret_cast<const float4*>(&As[kk][tr]);
            float4 a1 = *reinterpret_cast<const float4*>(&As[kk][tr + 4]);
            float4 b0 = *reinterpret_cast<const float4*>(&Bs[kk][tc]);
            float4 b1 = *reinterpret_cast<const float4*>(&Bs[kk][tc + 4]);
            const float ar[TM] = {a0.x, a0.y, a0.z, a0.w, a1.x, a1.y, a1.z, a1.w};
            const float bc[TN] = {b0.x, b0.y, b0.z, b0.w, b1.x, b1.y, b1.z, b1.w};
#pragma unroll
            for (int i = 0; i < TM; ++i)
#pragma unroll
                for (int j = 0; j < TN; ++j)
                    acc[i][j] = fmaf(ar[i], bc[j], acc[i][j]);
        }
        __syncthreads();
    }

#pragma unroll
    for (int i = 0; i < TM; ++i) {
        const int row = bm + tr + i;
        if (row < M) {
#pragma unroll
            for (int j = 0; j < TN; j += 4) {
                const int col = bn + tc + j;
                float4 v;
                v.x = acc[i][j + 0] + bias[col + 0];
                v.y = acc[i][j + 1] + bias[col + 1];
                v.z = acc[i][j + 2] + bias[col + 2];
                v.w = acc[i][j + 3] + bias[col + 3];
                *reinterpret_cast<float4*>(&C[(size_t)row * N + col]) = v;
            }
        }
    }
}

// ---------------------------------------------------------------------------
// Deformable-attention sampling, two-phase.
// Block = 2 queries, 256 threads, grid = M/2 (M even).
//
// Phase 1: thread <-> (qs, h, ip) with qs=t>>7, h=(t>>4)&7, ip=t&15.
//   Computes softmax weight (16-lane shfl reduction), bilinear corner
//   weights (validity folded: w=0), and 4 clamped corner BYTE offsets into
//   `value` (n*LIN*256 + (st + y*W + x)*256 + h*32 elements, x4 bytes).
//   Stores int4 + float4 to LDS.
// Phase 2: thread <-> (h, d) with h=t>>5, d=t&31; loops qs, 16 points:
//   broadcast LDS int4/float4 reads, 4 gathers, 4 fmas.
// ---------------------------------------------------------------------------
__global__ __launch_bounds__(256) void msda_sample(
    const float* __restrict__ value,
    const float* __restrict__ offs,
    const float* __restrict__ attr,
    const float* __restrict__ refp,
    float* __restrict__ out)
{
    __shared__ int   sIdx[2][HDN][16][4];
    __shared__ float sWgt[2][HDN][16][4];

    const int t = threadIdx.x;

    // ---------------- Phase 1 ----------------
    {
        const int qs = t >> 7;
        const int h  = (t >> 4) & 7;
        const int ip = t & 15;
        const int l  = ip >> 2;

        const int r = blockIdx.x * 2 + qs;
        const int n = r / LQ;

        const float logit = attr[(size_t)r * 128 + h * 16 + ip];
        float m = logit;
#pragma unroll
        for (int k = 8; k >= 1; k >>= 1) m = fmaxf(m, __shfl_xor(m, k));
        const float e = __expf(logit - m);
        float s = e;
#pragma unroll
        for (int k = 8; k >= 1; k >>= 1) s += __shfl_xor(s, k);
        const float aw = e / s;

        const float ox = offs[(size_t)r * 256 + h * 32 + ip * 2 + 0];
        const float oy = offs[(size_t)r * 256 + h * 32 + ip * 2 + 1];
        const float rx = refp[(size_t)r * 8 + l * 2 + 0];
        const float ry = refp[(size_t)r * 8 + l * 2 + 1];

        const int   Ww = cW[l], Hh = cH[l], st = cS[l];
        const float Wf = cWf[l], Hf = cHf[l];
        const float rW = cRW[l], rH = cRH[l];

        const float x = (rx + ox * rW) * Wf - 0.5f;
        const float y = (ry + oy * rH) * Hf - 0.5f;
        const float x0f = floorf(x);
        const float y0f = floorf(y);
        const float fx = x - x0f;
        const float fy = y - y0f;
        const int x0 = (int)x0f, y0 = (int)y0f;
        const int x1 = x0 + 1,   y1 = y0 + 1;

        const bool vx0 = (x0 >= 0) & (x0 < Ww);
        const bool vx1 = (x1 >= 0) & (x1 < Ww);
        const bool vy0 = (y0 >= 0) & (y0 < Hh);
        const bool vy1 = (y1 >= 0) & (y1 < Hh);

        const float gx0 = 1.f - fx, gx1 = fx;
        const float gy0 = 1.f - fy, gy1 = fy;

        const float w00 = (vx0 & vy0) ? gx0 * gy0 * aw : 0.f;
        const float w10 = (vx1 & vy0) ? gx1 * gy0 * aw : 0.f;
        const float w01 = (vx0 & vy1) ? gx0 * gy1 * aw : 0.f;
        const float w11 = (vx1 & vy1) ? gx1 * gy1 * aw : 0.f;

        const int xc0 = min(max(x0, 0), Ww - 1);
        const int xc1 = min(max(x1, 0), Ww - 1);
        const int yc0 = min(max(y0, 0), Hh - 1);
        const int yc1 = min(max(y1, 0), Hh - 1);

        // byte offsets into value[], h*32 channel base folded in
        const int base = (n * LIN + st) * CCH + h * DCH;
        const int i00 = (base + (yc0 * Ww + xc0) * CCH) * 4;
        const int i10 = (base + (yc0 * Ww + xc1) * CCH) * 4;
        const int i01 = (base + (yc1 * Ww + xc0) * CCH) * 4;
        const int i11 = (base + (yc1 * Ww + xc1) * CCH) * 4;

        sIdx[qs][h][ip][0] = i00;
        sIdx[qs][h][ip][1] = i10;
        sIdx[qs][h][ip][2] = i01;
        sIdx[qs][h][ip][3] = i11;
        sWgt[qs][h][ip][0] = w00;
        sWgt[qs][h][ip][1] = w10;
        sWgt[qs][h][ip][2] = w01;
        sWgt[qs][h][ip][3] = w11;
    }

    __syncthreads();

    // ---------------- Phase 2 ----------------
    const int h = t >> 5;
    const int d = t & 31;
    const char* vbase = (const char*)value + (size_t)d * 4;

#pragma unroll
    for (int qs = 0; qs < 2; ++qs) {
        const int r = blockIdx.x * 2 + qs;
        float acc = 0.f;
#pragma unroll
        for (int ip = 0; ip < 16; ++ip) {
            const int4   id = *reinterpret_cast<const int4*>(&sIdx[qs][h][ip][0]);
            const float4 w  = *reinterpret_cast<const float4*>(&sWgt[qs][h][ip][0]);
            acc = fmaf(w.x, *reinterpret_cast<const float*>(vbase + id.x), acc);
            acc = fmaf(w.y, *reinterpret_cast<const float*>(vbase + id.y), acc);
            acc = fmaf(w.z, *reinterpret_cast<const float*>(vbase + id.z), acc);
            acc = fmaf(w.w, *reinterpret_cast<const float*>(vbase + id.w), acc);
        }
        out[(size_t)r * 256 + t] = acc;
    }
}

// ---------------------------------------------------------------------------
extern "C" void kernel_launch(void* const* d_in, const int* in_sizes, int n_in,
                              void* d_out, int out_size, void* d_ws, size_t ws_size,
                              hipStream_t stream)
{
    const float* query  = (const float*)d_in[0];
    const float* refp   = (const float*)d_in[1];
    const float* inflat = (const float*)d_in[2];
    const float* Wv     = (const float*)d_in[5];
    const float* bv     = (const float*)d_in[6];
    const float* Woff   = (const float*)d_in[7];
    const float* boff   = (const float*)d_in[8];
    const float* Watt   = (const float*)d_in[9];
    const float* batt   = (const float*)d_in[10];
    const float* Wout   = (const float*)d_in[11];
    const float* bout   = (const float*)d_in[12];
    float* out = (float*)d_out;

    const int M = NB * LQ;                 // 35642
    float* ws    = (float*)d_ws;
    float* value = ws;                              // M*256
    float* offsW = value + (size_t)M * 256;         // M*256
    float* attrW = offsW + (size_t)M * 256;         // M*128
    float* oattn = attrW + (size_t)M * 128;         // M*256

    const dim3 blk(256);
    const int mblk = (M + BM - 1) / BM;    // 279

    gemm_f32<<<dim3(2, mblk), blk, 0, stream>>>(inflat, Wv,   bv,   value, M, 256, 256);
    gemm_f32<<<dim3(2, mblk), blk, 0, stream>>>(query,  Woff, boff, offsW, M, 256, 256);
    gemm_f32<<<dim3(1, mblk), blk, 0, stream>>>(query,  Watt, batt, attrW, M, 128, 256);

    msda_sample<<<dim3(M / 2), blk, 0, stream>>>(value, offsW, attrW, refp, oattn);

    gemm_f32<<<dim3(2, mblk), blk, 0, stream>>>(oattn, Wout, bout, out, M, 256, 256);
}

// Round 3
// 403.399 us; speedup vs baseline: 1.7149x; 1.5059x over previous
//
#include <hip/hip_runtime.h>
#include <hip/hip_bf16.h>
#include <math.h>

// Problem constants (fixed by the reference's setup_inputs)
#define NB    2
#define LQ    17821
#define LIN   17821
#define CCH   256
#define HDN   8
#define DCH   32
#define LVL   4
#define NPT   4

__constant__ const int   cH[LVL]  = {100, 50, 25, 13};
__constant__ const int   cW[LVL]  = {134, 67, 34, 17};
__constant__ const int   cS[LVL]  = {0, 13400, 16750, 17600};
__constant__ const float cHf[LVL] = {100.f, 50.f, 25.f, 13.f};
__constant__ const float cWf[LVL] = {134.f, 67.f, 34.f, 17.f};
__constant__ const float cRH[LVL] = {1.f/100.f, 1.f/50.f, 1.f/25.f, 1.f/13.f};
__constant__ const float cRW[LVL] = {1.f/134.f, 1.f/67.f, 1.f/34.f, 1.f/17.f};

// ---------------------------------------------------------------------------
// Classic fp32 SGEMM: C[M,N] = A[M,K] @ B[K,N] + bias[N]
// BM=BN=128, BK=8, 256 threads, 8x8 microtile. Requires N%128==0, K%8==0.
// ---------------------------------------------------------------------------
#define BM 128
#define BN 128
#define BK 8
#define TM 8
#define TN 8

__global__ __launch_bounds__(256, 2) void gemm_f32(
    const float* __restrict__ A, const float* __restrict__ B,
    const float* __restrict__ bias, float* __restrict__ C,
    int M, int N, int K)
{
    __shared__ float As[BK][BM];   // A tile stored transposed: As[k][m]
    __shared__ float Bs[BK][BN];

    const int tid = threadIdx.x;
    const int bm = blockIdx.y * BM;
    const int bn = blockIdx.x * BN;

    const int tr = (tid >> 4) * TM;
    const int tc = (tid & 15) * TN;

    const int a_r = tid >> 1;
    const int a_c = (tid & 1) * 4;
    const int b_r = tid >> 5;
    const int b_c = (tid & 31) * 4;

    float acc[TM][TN] = {};

    for (int k0 = 0; k0 < K; k0 += BK) {
        float4 av = make_float4(0.f, 0.f, 0.f, 0.f);
        if (bm + a_r < M)
            av = *reinterpret_cast<const float4*>(&A[(size_t)(bm + a_r) * K + k0 + a_c]);
        As[a_c + 0][a_r] = av.x;
        As[a_c + 1][a_r] = av.y;
        As[a_c + 2][a_r] = av.z;
        As[a_c + 3][a_r] = av.w;

        float4 bv4 = *reinterpret_cast<const float4*>(&B[(size_t)(k0 + b_r) * N + bn + b_c]);
        *reinterpret_cast<float4*>(&Bs[b_r][b_c]) = bv4;

        __syncthreads();

#pragma unroll
        for (int kk = 0; kk < BK; ++kk) {
            float4 a0 = *reinterpret_cast<const float4*>(&As[kk][tr]);
            float4 a1 = *reinterpret_cast<const float4*>(&As[kk][tr + 4]);
            float4 b0 = *reinterpret_cast<const float4*>(&Bs[kk][tc]);
            float4 b1 = *reinterpret_cast<const float4*>(&Bs[kk][tc + 4]);
            const float ar[TM] = {a0.x, a0.y, a0.z, a0.w, a1.x, a1.y, a1.z, a1.w};
            const float bc[TN] = {b0.x, b0.y, b0.z, b0.w, b1.x, b1.y, b1.z, b1.w};
#pragma unroll
            for (int i = 0; i < TM; ++i)
#pragma unroll
                for (int j = 0; j < TN; ++j)
                    acc[i][j] = fmaf(ar[i], bc[j], acc[i][j]);
        }
        __syncthreads();
    }

#pragma unroll
    for (int i = 0; i < TM; ++i) {
        const int row = bm + tr + i;
        if (row < M) {
#pragma unroll
            for (int j = 0; j < TN; j += 4) {
                const int col = bn + tc + j;
                float4 v;
                v.x = acc[i][j + 0] + bias[col + 0];
                v.y = acc[i][j + 1] + bias[col + 1];
                v.z = acc[i][j + 2] + bias[col + 2];
                v.w = acc[i][j + 3] + bias[col + 3];
                *reinterpret_cast<float4*>(&C[(size_t)row * N + col]) = v;
            }
        }
    }
}

// ---------------------------------------------------------------------------
// Deformable-attention sampling, two-phase, wide gathers.
// Block = 2 queries, 256 threads, grid = M/2 (M even).
//
// Phase 1: thread <-> (qs, h, ip): softmax weight (16-lane shfl), bilinear
//   corner weights (validity folded in), 4 clamped corner BYTE offsets into
//   value (n/level/head bases folded). -> LDS int4 + float4.
//
// Phase 2: thread <-> (h=g, corner c=(t>>3)&3, chunk sub=t&7).
//   Per (qs, ip): ONE global_load_dwordx4 per 32-lane group covers all 4
//   corners x 128B. Corner partials accumulate per-lane over all 16 points,
//   then one float4 butterfly reduce (xor 8,16) per qs, 8-lane f4 store.
// ---------------------------------------------------------------------------
__global__ __launch_bounds__(256) void msda_sample(
    const float* __restrict__ value,
    const float* __restrict__ offs,
    const float* __restrict__ attr,
    const float* __restrict__ refp,
    float* __restrict__ out)
{
    __shared__ int   sIdx[2][HDN][16][4];
    __shared__ float sWgt[2][HDN][16][4];

    const int t = threadIdx.x;

    // ---------------- Phase 1 ----------------
    {
        const int qs = t >> 7;
        const int h  = (t >> 4) & 7;
        const int ip = t & 15;
        const int l  = ip >> 2;

        const int r = blockIdx.x * 2 + qs;
        const int n = r / LQ;

        const float logit = attr[(size_t)r * 128 + h * 16 + ip];
        float m = logit;
#pragma unroll
        for (int k = 8; k >= 1; k >>= 1) m = fmaxf(m, __shfl_xor(m, k));
        const float e = __expf(logit - m);
        float s = e;
#pragma unroll
        for (int k = 8; k >= 1; k >>= 1) s += __shfl_xor(s, k);
        const float aw = e / s;

        const float ox = offs[(size_t)r * 256 + h * 32 + ip * 2 + 0];
        const float oy = offs[(size_t)r * 256 + h * 32 + ip * 2 + 1];
        const float rx = refp[(size_t)r * 8 + l * 2 + 0];
        const float ry = refp[(size_t)r * 8 + l * 2 + 1];

        const int   Ww = cW[l], Hh = cH[l], st = cS[l];
        const float Wf = cWf[l], Hf = cHf[l];
        const float rW = cRW[l], rH = cRH[l];

        const float x = (rx + ox * rW) * Wf - 0.5f;
        const float y = (ry + oy * rH) * Hf - 0.5f;
        const float x0f = floorf(x);
        const float y0f = floorf(y);
        const float fx = x - x0f;
        const float fy = y - y0f;
        const int x0 = (int)x0f, y0 = (int)y0f;
        const int x1 = x0 + 1,   y1 = y0 + 1;

        const bool vx0 = (x0 >= 0) & (x0 < Ww);
        const bool vx1 = (x1 >= 0) & (x1 < Ww);
        const bool vy0 = (y0 >= 0) & (y0 < Hh);
        const bool vy1 = (y1 >= 0) & (y1 < Hh);

        const float gx0 = 1.f - fx, gx1 = fx;
        const float gy0 = 1.f - fy, gy1 = fy;

        const float w00 = (vx0 & vy0) ? gx0 * gy0 * aw : 0.f;
        const float w10 = (vx1 & vy0) ? gx1 * gy0 * aw : 0.f;
        const float w01 = (vx0 & vy1) ? gx0 * gy1 * aw : 0.f;
        const float w11 = (vx1 & vy1) ? gx1 * gy1 * aw : 0.f;

        const int xc0 = min(max(x0, 0), Ww - 1);
        const int xc1 = min(max(x1, 0), Ww - 1);
        const int yc0 = min(max(y0, 0), Hh - 1);
        const int yc1 = min(max(y1, 0), Hh - 1);

        // byte offsets into value[], head channel base folded in
        const int base = (n * LIN + st) * CCH + h * DCH;
        sIdx[qs][h][ip][0] = (base + (yc0 * Ww + xc0) * CCH) * 4;
        sIdx[qs][h][ip][1] = (base + (yc0 * Ww + xc1) * CCH) * 4;
        sIdx[qs][h][ip][2] = (base + (yc1 * Ww + xc0) * CCH) * 4;
        sIdx[qs][h][ip][3] = (base + (yc1 * Ww + xc1) * CCH) * 4;
        sWgt[qs][h][ip][0] = w00;
        sWgt[qs][h][ip][1] = w10;
        sWgt[qs][h][ip][2] = w01;
        sWgt[qs][h][ip][3] = w11;
    }

    __syncthreads();

    // ---------------- Phase 2 ----------------
    const int g   = t >> 5;        // head
    const int w   = t & 31;
    const int c   = w >> 3;        // corner
    const int sub = w & 7;         // 16B chunk within the 128B channel row
    const char* vbase = (const char*)value + sub * 16;

    float4 acc0 = make_float4(0.f, 0.f, 0.f, 0.f);
    float4 acc1 = make_float4(0.f, 0.f, 0.f, 0.f);

#pragma unroll
    for (int ip = 0; ip < 16; ++ip) {
        const int   id0 = sIdx[0][g][ip][c];
        const float wt0 = sWgt[0][g][ip][c];
        const int   id1 = sIdx[1][g][ip][c];
        const float wt1 = sWgt[1][g][ip][c];
        const float4 v0 = *reinterpret_cast<const float4*>(vbase + id0);
        const float4 v1 = *reinterpret_cast<const float4*>(vbase + id1);
        acc0.x = fmaf(wt0, v0.x, acc0.x);
        acc0.y = fmaf(wt0, v0.y, acc0.y);
        acc0.z = fmaf(wt0, v0.z, acc0.z);
        acc0.w = fmaf(wt0, v0.w, acc0.w);
        acc1.x = fmaf(wt1, v1.x, acc1.x);
        acc1.y = fmaf(wt1, v1.y, acc1.y);
        acc1.z = fmaf(wt1, v1.z, acc1.z);
        acc1.w = fmaf(wt1, v1.w, acc1.w);
    }

    // reduce corner partials across lanes (xor 8 and 16 stay in the 32-group)
#pragma unroll
    for (int k = 8; k <= 16; k <<= 1) {
        acc0.x += __shfl_xor(acc0.x, k);
        acc0.y += __shfl_xor(acc0.y, k);
        acc0.z += __shfl_xor(acc0.z, k);
        acc0.w += __shfl_xor(acc0.w, k);
        acc1.x += __shfl_xor(acc1.x, k);
        acc1.y += __shfl_xor(acc1.y, k);
        acc1.z += __shfl_xor(acc1.z, k);
        acc1.w += __shfl_xor(acc1.w, k);
    }

    if (c == 0) {
        const int r0 = blockIdx.x * 2;
        float* o0 = &out[(size_t)r0 * 256 + g * 32 + sub * 4];
        *reinterpret_cast<float4*>(o0) = acc0;
        *reinterpret_cast<float4*>(o0 + 256) = acc1;
    }
}

// ---------------------------------------------------------------------------
extern "C" void kernel_launch(void* const* d_in, const int* in_sizes, int n_in,
                              void* d_out, int out_size, void* d_ws, size_t ws_size,
                              hipStream_t stream)
{
    const float* query  = (const float*)d_in[0];
    const float* refp   = (const float*)d_in[1];
    const float* inflat = (const float*)d_in[2];
    const float* Wv     = (const float*)d_in[5];
    const float* bv     = (const float*)d_in[6];
    const float* Woff   = (const float*)d_in[7];
    const float* boff   = (const float*)d_in[8];
    const float* Watt   = (const float*)d_in[9];
    const float* batt   = (const float*)d_in[10];
    const float* Wout   = (const float*)d_in[11];
    const float* bout   = (const float*)d_in[12];
    float* out = (float*)d_out;

    const int M = NB * LQ;                 // 35642
    float* ws    = (float*)d_ws;
    float* value = ws;                              // M*256
    float* offsW = value + (size_t)M * 256;         // M*256
    float* attrW = offsW + (size_t)M * 256;         // M*128
    float* oattn = attrW + (size_t)M * 128;         // M*256

    const dim3 blk(256);
    const int mblk = (M + BM - 1) / BM;    // 279

    gemm_f32<<<dim3(2, mblk), blk, 0, stream>>>(inflat, Wv,   bv,   value, M, 256, 256);
    gemm_f32<<<dim3(2, mblk), blk, 0, stream>>>(query,  Woff, boff, offsW, M, 256, 256);
    gemm_f32<<<dim3(1, mblk), blk, 0, stream>>>(query,  Watt, batt, attrW, M, 128, 256);

    msda_sample<<<dim3(M / 2), blk, 0, stream>>>(value, offsW, attrW, refp, oattn);

    gemm_f32<<<dim3(2, mblk), blk, 0, stream>>>(oattn, Wout, bout, out, M, 256, 256);
}